// Round 2
// baseline (205.294 us; speedup 1.0000x reference)
//
#include <hip/hip_runtime.h>
#include <hip/hip_bf16.h>
#include <math.h>

namespace {

constexpr float PI_F     = 3.14159265358979323846f;
constexpr float TWO_PI_F = 6.28318530717958647692f;
constexpr float INV_2PI_F = 0.15915494309189533577f;
constexpr float ZC_F     = 0.86602540378443864676f;

__device__ __constant__ float d_BOUNDS[8] = {0.1f, 0.2f, 0.4f, 0.6f, 0.75f,
                                             0.8660254037844386f, 0.92f, 0.97f};
__device__ __constant__ float d_PARITY[6] = {1.f, -1.f, 1.f, 1.f, -1.f, -1.f};
__device__ __constant__ int d_LEGAL[9][6] = {
    {0, 0, 0, 1, 1, 1},
    {1, 0, 1, 0, 1, 1},
    {1, 1, 1, 0, 1, 1},
    {0, 1, 0, 1, 1, 1},
    {1, 1, 1, 1, 1, 1},
    {0, 1, 0, 1, 1, 1},
    {0, 1, 0, 1, 0, 0},
    {0, 1, 1, 1, 0, 0},
    {0, 1, 1, 1, 0, 0}};

__device__ __forceinline__ float wave_sum(float v) {
#pragma unroll
  for (int o = 32; o > 0; o >>= 1) v += __shfl_xor(v, o, 64);
  return v;
}

__device__ __forceinline__ float gelu_exact(float x) {
  return 0.5f * x * (1.0f + erff(x * 0.70710678118654752440f));
}

}  // namespace

// ---------------------------------------------------------------------------
// Encoder: theta = pi*tanh(x @ W_enc + b_enc), plus coh[b] and per-block
// partial sums of coh (for z of layer 0). 512 blocks x 1024 thr (16 waves),
// one row per wave, W_enc staged in LDS in 128-row k-tiles.
// ---------------------------------------------------------------------------
__global__ __launch_bounds__(1024) void enc_kernel(
    const float* __restrict__ x, const float* __restrict__ W_enc,
    const float* __restrict__ b_enc, float* __restrict__ theta,
    float* __restrict__ coh, float* __restrict__ part) {
  __shared__ float Wt[128 * 60];
  __shared__ float red[16];
  const int tid = threadIdx.x;
  const int wave = tid >> 6, lane = tid & 63;
  const int r = __builtin_amdgcn_readfirstlane(blockIdx.x * 16 + wave);
  float acc = 0.f;
  for (int kt = 0; kt < 4; ++kt) {
    __syncthreads();
    for (int t = tid; t < 7680; t += 1024) Wt[t] = W_enc[kt * 7680 + t];
    __syncthreads();
    const float* xr = x + r * 512 + kt * 128;
    if (lane < 60) {
#pragma unroll 8
      for (int kk = 0; kk < 128; ++kk) acc = fmaf(xr[kk], Wt[kk * 60 + lane], acc);
    }
  }
  float th = 0.f, c = 0.f, s = 0.f;
  if (lane < 60) {
    th = PI_F * tanhf(acc + b_enc[lane]);
    theta[r * 60 + lane] = th;
    c = __cosf(th);
    s = __sinf(th);
  }
  const float mc = wave_sum(c) * (1.f / 60.f);
  const float ms = wave_sum(s) * (1.f / 60.f);
  const float ch = sqrtf(mc * mc + ms * ms);
  if (lane == 0) { coh[r] = ch; red[wave] = ch; }
  __syncthreads();
  if (tid == 0) {
    float t0 = 0.f;
#pragma unroll
    for (int w = 0; w < 16; ++w) t0 += red[w];
    part[blockIdx.x] = t0;
  }
}

// ---------------------------------------------------------------------------
// Per-layer decision: z = mean(coh); tier; row-0 MLP -> idx; K_eff, om_eff,
// coef/dmask scalars. Single block of 256 threads (tiny).
// ---------------------------------------------------------------------------
__global__ __launch_bounds__(256) void decide_kernel(
    const float* __restrict__ part, int np,
    const float* __restrict__ theta, const float* __restrict__ coh,
    const float* __restrict__ K, const float* __restrict__ omega,
    const float* __restrict__ aplK, const float* __restrict__ aplOm,
    const float* __restrict__ W1, const float* __restrict__ b1,
    const float* __restrict__ W2, const float* __restrict__ b2,
    const float* __restrict__ W3, const float* __restrict__ b3,
    const float* __restrict__ prior,
    float* __restrict__ KEFF, float* __restrict__ OMEFF,
    float* __restrict__ SCAL, int l) {
  __shared__ float red[256];
  __shared__ float feats[64], h1s[64], h2s[64], logits[6];
  __shared__ float sh_z, sh_kfac, sh_omadd;
  const int tid = threadIdx.x;
  float s = 0.f;
  for (int t = tid; t < np; t += 256) s += part[t];
  red[tid] = s;
  __syncthreads();
  for (int o = 128; o > 0; o >>= 1) {
    if (tid < o) red[tid] += red[tid + o];
    __syncthreads();
  }
  if (tid == 0) sh_z = red[0] * (1.f / 8192.f);
  __syncthreads();
  const float z = sh_z;
  int tier = 0;
#pragma unroll
  for (int i = 0; i < 8; ++i) tier += (z >= d_BOUNDS[i]) ? 1 : 0;
  const float dsneg = expf(-36.f * (z - ZC_F) * (z - ZC_F));
  if (tid < 60) feats[tid] = cosf(theta[tid]);
  if (tid == 60) feats[60] = z;
  if (tid == 61) feats[61] = coh[0];
  if (tid == 62) feats[62] = dsneg;
  if (tid == 63) feats[63] = (float)(tier + 1) * (1.f / 9.f);
  __syncthreads();
  if (tid < 64) {
    float a = b1[l * 64 + tid];
    for (int k = 0; k < 64; ++k) a = fmaf(feats[k], W1[l * 4096 + k * 64 + tid], a);
    h1s[tid] = gelu_exact(a);
  }
  __syncthreads();
  if (tid < 64) {
    float a = b2[l * 64 + tid];
    for (int k = 0; k < 64; ++k) a = fmaf(h1s[k], W2[l * 4096 + k * 64 + tid], a);
    h2s[tid] = gelu_exact(a);
  }
  __syncthreads();
  if (tid < 6) {
    float a = b3[l * 6 + tid] + prior[l * 6 + tid];
    for (int k = 0; k < 64; ++k) a = fmaf(h2s[k], W3[l * 384 + k * 6 + tid], a);
    logits[tid] = a;
  }
  __syncthreads();
  if (tid == 0) {
    float best = -INFINITY;
    int idx = 0;
#pragma unroll
    for (int m = 0; m < 6; ++m)
      if (d_LEGAL[tier][m] && logits[m] > best) { best = logits[m]; idx = m; }
    const float par = d_PARITY[idx];
    SCAL[0] = (idx == 1) ? 0.1f : ((idx == 5) ? -0.1f : 0.f);  // coef
    SCAL[1] = (idx == 4) ? 1.f : 0.f;                          // dmask
    sh_kfac = 1.f + par * (aplK[l * 6 + idx] * z) * 0.5f;
    sh_omadd = aplOm[l * 6 + idx] * par;
  }
  __syncthreads();
  const float kfac = sh_kfac;
  for (int t = tid; t < 3600; t += 256) KEFF[t] = K[l * 3600 + t] * kfac;
  if (tid < 60) OMEFF[tid] = omega[l * 60 + tid] + sh_omadd;
}

// ---------------------------------------------------------------------------
// Kuramoto: one wave per batch row, lane = oscillator. K_eff row in 60 VGPRs
// (fully unrolled), per-wave sin/cos pairs broadcast from LDS (float4,
// uniform-address). sin(th_j - th_i) factorized: csum_i = c_i*(K s)_i -
// s_i*(K c)_i. Wrap via thn - 2pi*rint(thn/2pi) == atan2(sin,cos).
// 2048 blocks x 256 thr (4 waves, 4 rows/block, exact cover of B=8192).
// ---------------------------------------------------------------------------
__global__ __launch_bounds__(256) void kura_kernel(
    float* __restrict__ theta, float* __restrict__ coh,
    const float* __restrict__ noise_l, const float* __restrict__ KEFF,
    const float* __restrict__ OMEFF, const float* __restrict__ SCAL,
    const float* __restrict__ Kglob, int l, float* __restrict__ part) {
  __shared__ float Klds[64 * 61];  // padded stride 61: conflict-free row reads
  __shared__ __align__(16) float scbuf[4][128];
  __shared__ float red[4];
  const int tid = threadIdx.x;
  const int wave = tid >> 6, lane = tid & 63;
  for (int t = tid; t < 3600; t += 256) Klds[(t / 60) * 61 + (t % 60)] = KEFF[t];
  __syncthreads();
  float kreg[60];
#pragma unroll
  for (int j = 0; j < 60; ++j) {
    float v = Klds[lane * 61 + j];  // lane 60..63 reads in-bounds garbage
    kreg[j] = (lane < 60) ? v : 0.f;
  }
  const float coef = SCAL[0];
  const float dmask = SCAL[1];
  const float om = (lane < 60) ? OMEFF[lane] : 0.f;
  const float kgN = Kglob[l] / 60.f;
  const int r = __builtin_amdgcn_readfirstlane(blockIdx.x * 4 + wave);
  float th = (lane < 60) ? theta[r * 60 + lane] : 0.f;
  const float ch = coh[r];
  const float m = wave_sum(th) * (1.f / 60.f);
  th += coef * __sinf(m - th);
  if (dmask != 0.f) {
    float nz = (lane < 60) ? noise_l[r * 60 + lane] : 0.f;
    th = fmaf(0.05f * nz, 1.f - ch, th);
  }
  float* sc = scbuf[wave];
  for (int step = 0; step < 10; ++step) {
    const float si = __sinf(th), ci = __cosf(th);
    *reinterpret_cast<float2*>(&sc[2 * lane]) = make_float2(si, ci);
    __builtin_amdgcn_wave_barrier();  // keep reads after writes (wave-local LDS)
    float accs = 0.f, accc = 0.f;
#pragma unroll
    for (int t = 0; t < 30; ++t) {
      const float4 p = *reinterpret_cast<const float4*>(&sc[4 * t]);
      accs = fmaf(kreg[2 * t], p.x, accs);
      accc = fmaf(kreg[2 * t], p.y, accc);
      accs = fmaf(kreg[2 * t + 1], p.z, accs);
      accc = fmaf(kreg[2 * t + 1], p.w, accc);
    }
    __builtin_amdgcn_wave_barrier();  // next iter's writes stay after reads
    const float csum = ci * accs - si * accc;
    const float thn = fmaf(0.1f, fmaf(kgN, csum, om), th);
    th = fmaf(-TWO_PI_F, rintf(thn * INV_2PI_F), thn);
  }
  const float c2 = (lane < 60) ? __cosf(th) : 0.f;
  const float s2 = (lane < 60) ? __sinf(th) : 0.f;
  const float mc = wave_sum(c2) * (1.f / 60.f);
  const float ms = wave_sum(s2) * (1.f / 60.f);
  const float chn = sqrtf(mc * mc + ms * ms);
  if (lane < 60) theta[r * 60 + lane] = th;
  if (lane == 0) { coh[r] = chn; red[wave] = chn; }
  __syncthreads();
  if (tid == 0) part[blockIdx.x] = red[0] + red[1] + red[2] + red[3];
}

// ---------------------------------------------------------------------------
// Output: out = ([cos th, sin th] @ W_out + b_out) * coh  (float32 output).
// 512 blocks x 256 thr; 16 rows/block staged as cos/sin in LDS; thread d
// owns output column d.
// ---------------------------------------------------------------------------
__global__ __launch_bounds__(256) void out_kernel(
    const float* __restrict__ theta, const float* __restrict__ coh,
    const float* __restrict__ W_out, const float* __restrict__ b_out,
    float* __restrict__ out) {
  __shared__ __align__(16) float sc[16][120];
  __shared__ float cohl[16];
  const int tid = threadIdx.x;
  const int b0 = blockIdx.x * 16;
  for (int t = tid; t < 960; t += 256) {
    const int r = t / 60, n = t % 60;
    const float th = theta[(b0 + r) * 60 + n];
    sc[r][n] = __cosf(th);
    sc[r][60 + n] = __sinf(th);
  }
  if (tid < 16) cohl[tid] = coh[b0 + tid];
  __syncthreads();
  float acc[16];
#pragma unroll
  for (int r = 0; r < 16; ++r) acc[r] = 0.f;
  const int d = tid;
  for (int t = 0; t < 30; ++t) {
    const float w0 = W_out[(4 * t + 0) * 256 + d];
    const float w1 = W_out[(4 * t + 1) * 256 + d];
    const float w2 = W_out[(4 * t + 2) * 256 + d];
    const float w3 = W_out[(4 * t + 3) * 256 + d];
#pragma unroll
    for (int r = 0; r < 16; ++r) {
      const float4 p = *reinterpret_cast<const float4*>(&sc[r][4 * t]);
      acc[r] = fmaf(p.w, w3, fmaf(p.z, w2, fmaf(p.y, w1, fmaf(p.x, w0, acc[r]))));
    }
  }
  const float bo = b_out[d];
#pragma unroll
  for (int r = 0; r < 16; ++r)
    out[(size_t)(b0 + r) * 256 + d] = (acc[r] + bo) * cohl[r];
}

// ---------------------------------------------------------------------------
// Workspace layout (floats):
//   theta  [8192*60]  @ 0
//   coh    [8192]     @ 491520
//   part   [5*2048]   @ 499712   (stage s = partial coh sums feeding layer s)
//   keff   [3600]     @ 509952
//   omeff  [64]       @ 513552
//   scal   [8]        @ 513616   -> total ~2.06 MB
// ---------------------------------------------------------------------------
extern "C" void kernel_launch(void* const* d_in, const int* in_sizes, int n_in,
                              void* d_out, int out_size, void* d_ws, size_t ws_size,
                              hipStream_t stream) {
  const float* x     = (const float*)d_in[0];
  const float* W_enc = (const float*)d_in[1];
  const float* b_enc = (const float*)d_in[2];
  const float* K     = (const float*)d_in[3];
  const float* omega = (const float*)d_in[4];
  const float* Kglob = (const float*)d_in[5];
  const float* aplK  = (const float*)d_in[6];
  const float* aplOm = (const float*)d_in[7];
  const float* W1    = (const float*)d_in[8];
  const float* b1    = (const float*)d_in[9];
  const float* W2    = (const float*)d_in[10];
  const float* b2    = (const float*)d_in[11];
  const float* W3    = (const float*)d_in[12];
  const float* b3    = (const float*)d_in[13];
  const float* prior = (const float*)d_in[14];
  const float* noise = (const float*)d_in[15];
  const float* W_out = (const float*)d_in[16];
  const float* b_out = (const float*)d_in[17];

  float* ws    = (float*)d_ws;
  float* theta = ws;
  float* coh   = ws + 491520;
  float* part  = ws + 499712;
  float* keff  = ws + 509952;
  float* omeff = ws + 513552;
  float* scal  = ws + 513616;

  enc_kernel<<<512, 1024, 0, stream>>>(x, W_enc, b_enc, theta, coh, part);
  for (int l = 0; l < 4; ++l) {
    decide_kernel<<<1, 256, 0, stream>>>(part + l * 2048, (l == 0) ? 512 : 2048,
                                         theta, coh, K, omega, aplK, aplOm,
                                         W1, b1, W2, b2, W3, b3, prior,
                                         keff, omeff, scal, l);
    kura_kernel<<<2048, 256, 0, stream>>>(theta, coh,
                                          noise + (size_t)l * 8192 * 60,
                                          keff, omeff, scal, Kglob, l,
                                          part + (l + 1) * 2048);
  }
  out_kernel<<<512, 256, 0, stream>>>(theta, coh, W_out, b_out,
                                      (float*)d_out);
}

// Round 3
// 117.613 us; speedup vs baseline: 1.7455x; 1.7455x over previous
//
#include <hip/hip_runtime.h>
#include <hip/hip_bf16.h>
#include <math.h>

typedef __attribute__((ext_vector_type(8))) short bf16x8v;
typedef __attribute__((ext_vector_type(4))) float f32x4v;

namespace {

constexpr float PI_F      = 3.14159265358979323846f;
constexpr float TWO_PI_F  = 6.28318530717958647692f;
constexpr float INV_2PI_F = 0.15915494309189533577f;
constexpr float ZC_F      = 0.86602540378443864676f;

__device__ __constant__ float d_BOUNDS[8] = {0.1f, 0.2f, 0.4f, 0.6f, 0.75f,
                                             0.8660254037844386f, 0.92f, 0.97f};
__device__ __constant__ float d_PARITY[6] = {1.f, -1.f, 1.f, 1.f, -1.f, -1.f};
__device__ __constant__ int d_LEGAL[9][6] = {
    {0, 0, 0, 1, 1, 1},
    {1, 0, 1, 0, 1, 1},
    {1, 1, 1, 0, 1, 1},
    {0, 1, 0, 1, 1, 1},
    {1, 1, 1, 1, 1, 1},
    {0, 1, 0, 1, 1, 1},
    {0, 1, 0, 1, 0, 0},
    {0, 1, 1, 1, 0, 0},
    {0, 1, 1, 1, 0, 0}};

__device__ __forceinline__ float wave_sum(float v) {
#pragma unroll
  for (int o = 32; o > 0; o >>= 1) v += __shfl_xor(v, o, 64);
  return v;
}

__device__ __forceinline__ float gelu_exact(float x) {
  return 0.5f * x * (1.0f + erff(x * 0.70710678118654752440f));
}

// pack two f32 -> one dword of two bf16 (compiler emits v_cvt_pk_bf16_f32)
__device__ __forceinline__ unsigned pkbf(float a, float b) {
  union { struct { __hip_bfloat16 x, y; } p; unsigned u; } t;
  t.p.x = __float2bfloat16(a);
  t.p.y = __float2bfloat16(b);
  return t.u;
}

}  // namespace

// ---------------------------------------------------------------------------
// Encoder: theta = pi*tanh(x @ W_enc + b_enc) + coh + 512 partial coh sums.
// ---------------------------------------------------------------------------
__global__ __launch_bounds__(1024) void enc_kernel(
    const float* __restrict__ x, const float* __restrict__ W_enc,
    const float* __restrict__ b_enc, float* __restrict__ theta,
    float* __restrict__ coh, float* __restrict__ part) {
  __shared__ float Wt[128 * 60];
  __shared__ float red[16];
  const int tid = threadIdx.x;
  const int wave = tid >> 6, lane = tid & 63;
  const int r = __builtin_amdgcn_readfirstlane(blockIdx.x * 16 + wave);
  float acc = 0.f;
  for (int kt = 0; kt < 4; ++kt) {
    __syncthreads();
    for (int t = tid; t < 7680; t += 1024) Wt[t] = W_enc[kt * 7680 + t];
    __syncthreads();
    const float* xr = x + r * 512 + kt * 128;
    if (lane < 60) {
#pragma unroll 8
      for (int kk = 0; kk < 128; ++kk) acc = fmaf(xr[kk], Wt[kk * 60 + lane], acc);
    }
  }
  float th = 0.f, c = 0.f, s = 0.f;
  if (lane < 60) {
    th = PI_F * tanhf(acc + b_enc[lane]);
    theta[r * 60 + lane] = th;
    c = __cosf(th);
    s = __sinf(th);
  }
  const float mc = wave_sum(c) * (1.f / 60.f);
  const float ms = wave_sum(s) * (1.f / 60.f);
  const float ch = sqrtf(mc * mc + ms * ms);
  if (lane == 0) { coh[r] = ch; red[wave] = ch; }
  __syncthreads();
  if (tid == 0) {
    float t0 = 0.f;
#pragma unroll
    for (int w = 0; w < 16; ++w) t0 += red[w];
    part[blockIdx.x] = t0;
  }
}

// ---------------------------------------------------------------------------
// Per-layer decision. Produces:
//   KEFFB: bf16 [64][64] zero-padded A-matrix = K[l] * (kfac * DT * kg / N)
//   OM01 : f32 [64] = DT*(omega + omadd), pads 0
//   SCAL : coef, dmask
// ---------------------------------------------------------------------------
__global__ __launch_bounds__(256) void decide_kernel(
    const float* __restrict__ part, int np,
    const float* __restrict__ theta, const float* __restrict__ coh,
    const float* __restrict__ K, const float* __restrict__ omega,
    const float* __restrict__ Kglob,
    const float* __restrict__ aplK, const float* __restrict__ aplOm,
    const float* __restrict__ W1, const float* __restrict__ b1,
    const float* __restrict__ W2, const float* __restrict__ b2,
    const float* __restrict__ W3, const float* __restrict__ b3,
    const float* __restrict__ prior,
    unsigned short* __restrict__ KEFFB, float* __restrict__ OM01,
    float* __restrict__ SCAL, int l) {
  __shared__ float red[256];
  __shared__ float feats[64], h1s[64], h2s[64], logits[6];
  __shared__ float sh_z, sh_ktot, sh_omadd;
  const int tid = threadIdx.x;
  float s = 0.f;
  for (int t = tid; t < np; t += 256) s += part[t];
  red[tid] = s;
  __syncthreads();
  for (int o = 128; o > 0; o >>= 1) {
    if (tid < o) red[tid] += red[tid + o];
    __syncthreads();
  }
  if (tid == 0) sh_z = red[0] * (1.f / 8192.f);
  __syncthreads();
  const float z = sh_z;
  int tier = 0;
#pragma unroll
  for (int i = 0; i < 8; ++i) tier += (z >= d_BOUNDS[i]) ? 1 : 0;
  const float dsneg = expf(-36.f * (z - ZC_F) * (z - ZC_F));
  if (tid < 60) feats[tid] = cosf(theta[tid]);
  if (tid == 60) feats[60] = z;
  if (tid == 61) feats[61] = coh[0];
  if (tid == 62) feats[62] = dsneg;
  if (tid == 63) feats[63] = (float)(tier + 1) * (1.f / 9.f);
  __syncthreads();
  if (tid < 64) {
    float a = b1[l * 64 + tid];
    for (int k = 0; k < 64; ++k) a = fmaf(feats[k], W1[l * 4096 + k * 64 + tid], a);
    h1s[tid] = gelu_exact(a);
  }
  __syncthreads();
  if (tid < 64) {
    float a = b2[l * 64 + tid];
    for (int k = 0; k < 64; ++k) a = fmaf(h1s[k], W2[l * 4096 + k * 64 + tid], a);
    h2s[tid] = gelu_exact(a);
  }
  __syncthreads();
  if (tid < 6) {
    float a = b3[l * 6 + tid] + prior[l * 6 + tid];
    for (int k = 0; k < 64; ++k) a = fmaf(h2s[k], W3[l * 384 + k * 6 + tid], a);
    logits[tid] = a;
  }
  __syncthreads();
  if (tid == 0) {
    float best = -INFINITY;
    int idx = 0;
#pragma unroll
    for (int m = 0; m < 6; ++m)
      if (d_LEGAL[tier][m] && logits[m] > best) { best = logits[m]; idx = m; }
    const float par = d_PARITY[idx];
    SCAL[0] = (idx == 1) ? 0.1f : ((idx == 5) ? -0.1f : 0.f);  // coef
    SCAL[1] = (idx == 4) ? 1.f : 0.f;                          // dmask
    const float kfac = 1.f + par * (aplK[l * 6 + idx] * z) * 0.5f;
    sh_ktot = kfac * 0.1f * Kglob[l] * (1.f / 60.f);
    sh_omadd = aplOm[l * 6 + idx] * par;
  }
  __syncthreads();
  const float ktot = sh_ktot;
  for (int t = tid; t < 4096; t += 256) {
    const int i = t >> 6, j = t & 63;
    const float v = (i < 60 && j < 60) ? K[l * 3600 + i * 60 + j] * ktot : 0.f;
    const __hip_bfloat16 hb = __float2bfloat16(v);
    KEFFB[t] = __builtin_bit_cast(unsigned short, hb);
  }
  if (tid < 64)
    OM01[tid] = (tid < 60) ? 0.1f * (omega[l * 60 + tid] + sh_omadd) : 0.f;
}

// ---------------------------------------------------------------------------
// MFMA Kuramoto. 1 wave = 16 batch cols, M=64 osc (4 tiles), K=64 (2 ktiles).
// State in D-fragment layout: col = lane&15 (batch), row = 4*(lane>>4)+reg.
// A[row=l&15, k=8*(l>>4)+j]; B[k=8*(l>>4)+j, col=l&15]. D->B redistribution
// via ds_bpermute (__shfl) group permutation. sin/cos advanced by small-angle
// rotation (|delta|<0.05); theta tracked unwrapped, wrapped once at end.
// ---------------------------------------------------------------------------
__global__ __launch_bounds__(64) void kura_mfma(
    float* __restrict__ theta, float* __restrict__ coh,
    const float* __restrict__ noise_l, const unsigned short* __restrict__ keffb,
    const float* __restrict__ om01, const float* __restrict__ SCAL,
    float* __restrict__ part) {
  const int l = threadIdx.x;
  const int c = l & 15;
  const int g = l >> 4;
  const int b = blockIdx.x * 16 + c;
  const bool hi = (g >= 2);

  // A fragments: tile m rows 16m+c, k-octet 8g within k-tile kt.
  bf16x8v Af[4][2];
#pragma unroll
  for (int m = 0; m < 4; ++m)
#pragma unroll
    for (int kt = 0; kt < 2; ++kt)
      Af[m][kt] = *reinterpret_cast<const bf16x8v*>(
          keffb + (16 * m + c) * 64 + 32 * kt + 8 * g);

  float om[4][4], th[4][4], s[4][4], cc[4][4];
#pragma unroll
  for (int m = 0; m < 4; ++m)
#pragma unroll
    for (int r = 0; r < 4; ++r) {
      const int o = 16 * m + 4 * g + r;
      om[m][r] = om01[o];
      th[m][r] = (o < 60) ? theta[b * 60 + o] : 0.f;
    }

  // mean(theta) per batch col (pads are 0)
  float psum = 0.f;
#pragma unroll
  for (int m = 0; m < 4; ++m)
#pragma unroll
    for (int r = 0; r < 4; ++r) psum += th[m][r];
  psum += __shfl_xor(psum, 16);
  psum += __shfl_xor(psum, 32);
  const float mean = psum * (1.f / 60.f);

  const float coef = SCAL[0];
  const float dmask = SCAL[1];
  if (coef != 0.f) {
#pragma unroll
    for (int m = 0; m < 4; ++m)
#pragma unroll
      for (int r = 0; r < 4; ++r) {
        const int o = 16 * m + 4 * g + r;
        if (o < 60) th[m][r] += coef * __sinf(mean - th[m][r]);
      }
  }
  if (dmask != 0.f) {
    const float f = 0.05f * (1.f - coh[b]);
#pragma unroll
    for (int m = 0; m < 4; ++m)
#pragma unroll
      for (int r = 0; r < 4; ++r) {
        const int o = 16 * m + 4 * g + r;
        if (o < 60) th[m][r] = fmaf(f, noise_l[b * 60 + o], th[m][r]);
      }
  }
#pragma unroll
  for (int m = 0; m < 4; ++m)
#pragma unroll
    for (int r = 0; r < 4; ++r) {
      s[m][r] = __sinf(th[m][r]);   // pads: (0,1) exactly
      cc[m][r] = __cosf(th[m][r]);
    }

  const int srcA = ((2 * g) & 3) * 16 + c;
  const int srcB = ((2 * g + 1) & 3) * 16 + c;
  const f32x4v zero = {0.f, 0.f, 0.f, 0.f};

  for (int step = 0; step < 10; ++step) {
    // pack D-layout sin/cos to bf16 pairs (reg pairs (0,1),(2,3))
    unsigned sd[4][2], cd[4][2];
#pragma unroll
    for (int m = 0; m < 4; ++m)
#pragma unroll
      for (int p = 0; p < 2; ++p) {
        sd[m][p] = pkbf(s[m][2 * p], s[m][2 * p + 1]);
        cd[m][p] = pkbf(cc[m][2 * p], cc[m][2 * p + 1]);
      }
    // B fragments: dword slot {0,1} from srcA, {2,3} from srcB;
    // m_src = 2*kt + (g>>1) realized as 2 shuffles + select by half.
    union { unsigned u[4]; bf16x8v v; } BS[2], BC[2];
#pragma unroll
    for (int kt = 0; kt < 2; ++kt)
#pragma unroll
      for (int p = 0; p < 2; ++p) {
        unsigned a0 = (unsigned)__shfl((int)sd[2 * kt][p], srcA, 64);
        unsigned a1 = (unsigned)__shfl((int)sd[2 * kt + 1][p], srcA, 64);
        BS[kt].u[p] = hi ? a1 : a0;
        unsigned b0 = (unsigned)__shfl((int)sd[2 * kt][p], srcB, 64);
        unsigned b1 = (unsigned)__shfl((int)sd[2 * kt + 1][p], srcB, 64);
        BS[kt].u[2 + p] = hi ? b1 : b0;
        unsigned e0 = (unsigned)__shfl((int)cd[2 * kt][p], srcA, 64);
        unsigned e1 = (unsigned)__shfl((int)cd[2 * kt + 1][p], srcA, 64);
        BC[kt].u[p] = hi ? e1 : e0;
        unsigned f0 = (unsigned)__shfl((int)cd[2 * kt][p], srcB, 64);
        unsigned f1 = (unsigned)__shfl((int)cd[2 * kt + 1][p], srcB, 64);
        BC[kt].u[2 + p] = hi ? f1 : f0;
      }
    // P = A*sin, Q = A*cos (A pre-scaled by DT*kg/N*kfac)
    f32x4v P[4], Q[4];
#pragma unroll
    for (int m = 0; m < 4; ++m) {
      f32x4v t0 = __builtin_amdgcn_mfma_f32_16x16x32_bf16(Af[m][0], BS[0].v, zero, 0, 0, 0);
      P[m] = __builtin_amdgcn_mfma_f32_16x16x32_bf16(Af[m][1], BS[1].v, t0, 0, 0, 0);
      f32x4v t1 = __builtin_amdgcn_mfma_f32_16x16x32_bf16(Af[m][0], BC[0].v, zero, 0, 0, 0);
      Q[m] = __builtin_amdgcn_mfma_f32_16x16x32_bf16(Af[m][1], BC[1].v, t1, 0, 0, 0);
    }
    // delta = om' + c*P - s*Q ; advance (s,c) by rotation; track theta
#pragma unroll
    for (int m = 0; m < 4; ++m)
#pragma unroll
      for (int r = 0; r < 4; ++r) {
        const float d = om[m][r] + cc[m][r] * P[m][r] - s[m][r] * Q[m][r];
        th[m][r] += d;
        const float d2 = d * d;
        const float sdl = d * (1.f - d2 * (1.f / 6.f));
        const float cdl = 1.f - d2 * 0.5f;
        const float sn = s[m][r] * cdl + cc[m][r] * sdl;
        cc[m][r] = cc[m][r] * cdl - s[m][r] * sdl;
        s[m][r] = sn;
      }
  }

  // coherence (pads contribute cos=1 exactly -> subtract 4)
  float pc = 0.f, ps2 = 0.f;
#pragma unroll
  for (int m = 0; m < 4; ++m)
#pragma unroll
    for (int r = 0; r < 4; ++r) { pc += cc[m][r]; ps2 += s[m][r]; }
  pc += __shfl_xor(pc, 16);
  pc += __shfl_xor(pc, 32);
  ps2 += __shfl_xor(ps2, 16);
  ps2 += __shfl_xor(ps2, 32);
  const float mc = (pc - 4.f) * (1.f / 60.f);
  const float ms = ps2 * (1.f / 60.f);
  const float ch = sqrtf(mc * mc + ms * ms);

#pragma unroll
  for (int m = 0; m < 4; ++m)
#pragma unroll
    for (int r = 0; r < 4; ++r) {
      const int o = 16 * m + 4 * g + r;
      if (o < 60) {
        const float t = th[m][r];
        theta[b * 60 + o] = fmaf(-TWO_PI_F, rintf(t * INV_2PI_F), t);
      }
    }
  if (l < 16) coh[b] = ch;
  const float tot = wave_sum(ch);  // each col replicated 4x
  if (l == 0) part[blockIdx.x] = tot * 0.25f;
}

// ---------------------------------------------------------------------------
// Output: out = ([cos th, sin th] @ W_out + b_out) * coh  (f32).
// ---------------------------------------------------------------------------
__global__ __launch_bounds__(256) void out_kernel(
    const float* __restrict__ theta, const float* __restrict__ coh,
    const float* __restrict__ W_out, const float* __restrict__ b_out,
    float* __restrict__ out) {
  __shared__ __align__(16) float sc[16][120];
  __shared__ float cohl[16];
  const int tid = threadIdx.x;
  const int b0 = blockIdx.x * 16;
  for (int t = tid; t < 960; t += 256) {
    const int r = t / 60, n = t % 60;
    const float th = theta[(b0 + r) * 60 + n];
    sc[r][n] = __cosf(th);
    sc[r][60 + n] = __sinf(th);
  }
  if (tid < 16) cohl[tid] = coh[b0 + tid];
  __syncthreads();
  float acc[16];
#pragma unroll
  for (int r = 0; r < 16; ++r) acc[r] = 0.f;
  const int d = tid;
  for (int t = 0; t < 30; ++t) {
    const float w0 = W_out[(4 * t + 0) * 256 + d];
    const float w1 = W_out[(4 * t + 1) * 256 + d];
    const float w2 = W_out[(4 * t + 2) * 256 + d];
    const float w3 = W_out[(4 * t + 3) * 256 + d];
#pragma unroll
    for (int r = 0; r < 16; ++r) {
      const float4 p = *reinterpret_cast<const float4*>(&sc[r][4 * t]);
      acc[r] = fmaf(p.w, w3, fmaf(p.z, w2, fmaf(p.y, w1, fmaf(p.x, w0, acc[r]))));
    }
  }
  const float bo = b_out[d];
#pragma unroll
  for (int r = 0; r < 16; ++r)
    out[(size_t)(b0 + r) * 256 + d] = (acc[r] + bo) * cohl[r];
}

// ---------------------------------------------------------------------------
// Workspace (float offsets):
//   theta [491520] @0, coh [8192] @491520, part [5*512] @499712,
//   keffb [4096 ushort = 2048 f] @502272, om01 [64] @504320, scal [8] @504384
// ---------------------------------------------------------------------------
extern "C" void kernel_launch(void* const* d_in, const int* in_sizes, int n_in,
                              void* d_out, int out_size, void* d_ws, size_t ws_size,
                              hipStream_t stream) {
  const float* x     = (const float*)d_in[0];
  const float* W_enc = (const float*)d_in[1];
  const float* b_enc = (const float*)d_in[2];
  const float* K     = (const float*)d_in[3];
  const float* omega = (const float*)d_in[4];
  const float* Kglob = (const float*)d_in[5];
  const float* aplK  = (const float*)d_in[6];
  const float* aplOm = (const float*)d_in[7];
  const float* W1    = (const float*)d_in[8];
  const float* b1    = (const float*)d_in[9];
  const float* W2    = (const float*)d_in[10];
  const float* b2    = (const float*)d_in[11];
  const float* W3    = (const float*)d_in[12];
  const float* b3    = (const float*)d_in[13];
  const float* prior = (const float*)d_in[14];
  const float* noise = (const float*)d_in[15];
  const float* W_out = (const float*)d_in[16];
  const float* b_out = (const float*)d_in[17];

  float* ws    = (float*)d_ws;
  float* theta = ws;
  float* coh   = ws + 491520;
  float* part  = ws + 499712;
  unsigned short* keffb = (unsigned short*)(ws + 502272);
  float* om01  = ws + 504320;
  float* scal  = ws + 504384;

  enc_kernel<<<512, 1024, 0, stream>>>(x, W_enc, b_enc, theta, coh, part);
  for (int l = 0; l < 4; ++l) {
    decide_kernel<<<1, 256, 0, stream>>>(part + l * 512, 512,
                                         theta, coh, K, omega, Kglob, aplK, aplOm,
                                         W1, b1, W2, b2, W3, b3, prior,
                                         keffb, om01, scal, l);
    kura_mfma<<<512, 64, 0, stream>>>(theta, coh,
                                      noise + (size_t)l * 491520,
                                      keffb, om01, scal,
                                      part + (l + 1) * 512);
  }
  out_kernel<<<512, 256, 0, stream>>>(theta, coh, W_out, b_out,
                                      (float*)d_out);
}